// Round 1
// baseline (468.305 us; speedup 1.0000x reference)
//
#include <hip/hip_runtime.h>

// GCN 2-layer: out = A_norm @ relu(A_norm @ (x@W1) + b1) @ ... pattern
// A_norm includes self-loops; deg computed over targets (col) only.
// Strategy: int-histogram degree -> rsqrt; CSR build (scan + fill) to make
// aggregation atomic-free; fp32 LDS-tiled GEMM (no fp32 MFMA on CDNA4);
// wave-per-node aggregation with coalesced float2 gathers.

__global__ void k_zero_i32(int* __restrict__ p, int n) {
    int i = blockIdx.x * blockDim.x + threadIdx.x;
    if (i < n) p[i] = 0;
}

__global__ void k_count(const int* __restrict__ col, int* __restrict__ deg, int E) {
    int e = blockIdx.x * blockDim.x + threadIdx.x;
    if (e < E) atomicAdd(&deg[col[e]], 1);
}

__global__ void k_dis(const int* __restrict__ deg, float* __restrict__ dis, int n) {
    int i = blockIdx.x * blockDim.x + threadIdx.x;
    if (i < n) dis[i] = rsqrtf((float)deg[i] + 1.0f);  // +1 = self-loop
}

// Single-block inclusive scan over deg -> rowptr (exclusive form in rowptr[0..n]).
__global__ void k_scan(const int* __restrict__ deg, int* __restrict__ rowptr, int n) {
    __shared__ int sdata[1024];
    __shared__ int s_off;
    int tid = threadIdx.x;
    if (tid == 0) { s_off = 0; rowptr[0] = 0; }
    __syncthreads();
    for (int base = 0; base < n; base += 1024) {
        int v = (base + tid < n) ? deg[base + tid] : 0;
        sdata[tid] = v;
        __syncthreads();
        for (int off = 1; off < 1024; off <<= 1) {
            int t = (tid >= off) ? sdata[tid - off] : 0;
            __syncthreads();
            sdata[tid] += t;
            __syncthreads();
        }
        int incl = sdata[tid] + s_off;
        if (base + tid < n) rowptr[base + tid + 1] = incl;
        __syncthreads();
        if (tid == 1023) s_off = incl;
        __syncthreads();
    }
}

__global__ void k_fill(const int* __restrict__ row, const int* __restrict__ col,
                       const int* __restrict__ rowptr, int* __restrict__ cursor,
                       int* __restrict__ csr, int E) {
    int e = blockIdx.x * blockDim.x + threadIdx.x;
    if (e < E) {
        int c = col[e];
        int pos = atomicAdd(&cursor[c], 1);
        csr[rowptr[c] + pos] = row[e];
    }
}

// Y[M,Fw] = X[M,128] @ W[128,Fw]; tile BM=32 rows x BN=64 cols (blockIdx.y).
// Thread: colq=tid&31 -> cols {colq, colq+32}; rowq=tid>>5 -> rows {rowq+8r}.
// Per-wave LDS reads: x = 2 distinct addrs same bank (2-way, free per m136),
// w = 32 consecutive (conflict-free). LDS = 48 KB -> 3 blocks/CU.
__global__ __launch_bounds__(256) void k_gemm(const float* __restrict__ X,
                                              const float* __restrict__ W,
                                              float* __restrict__ Y, int M, int Fw) {
    __shared__ float wsh[128 * 64];
    __shared__ float xsh[32 * 128];
    int tid = threadIdx.x;
    int m0 = blockIdx.x * 32;
    int n0 = blockIdx.y * 64;
    for (int i = tid; i < 128 * 16; i += 256) {
        int k = i >> 4, c4 = (i & 15) << 2;
        *(float4*)&wsh[k * 64 + c4] = *(const float4*)&W[(size_t)k * Fw + n0 + c4];
    }
    for (int i = tid; i < 32 * 32; i += 256) {
        int r = i >> 5, k4 = (i & 31) << 2;
        int m = m0 + r;
        float4 v = make_float4(0.f, 0.f, 0.f, 0.f);
        if (m < M) v = *(const float4*)&X[(size_t)m * 128 + k4];
        *(float4*)&xsh[r * 128 + k4] = v;
    }
    __syncthreads();
    int colq = tid & 31, rowq = tid >> 5;
    float acc[4][2] = {};
#pragma unroll 4
    for (int k = 0; k < 128; ++k) {
        float w0 = wsh[k * 64 + colq];
        float w1 = wsh[k * 64 + colq + 32];
#pragma unroll
        for (int r = 0; r < 4; ++r) {
            float xv = xsh[(rowq + 8 * r) * 128 + k];
            acc[r][0] += xv * w0;
            acc[r][1] += xv * w1;
        }
    }
#pragma unroll
    for (int r = 0; r < 4; ++r) {
        int m = m0 + rowq + 8 * r;
        if (m < M) {
            Y[(size_t)m * Fw + n0 + colq] = acc[r][0];
            Y[(size_t)m * Fw + n0 + colq + 32] = acc[r][1];
        }
    }
}

// One wave per node; F=128 -> float2/lane, F=64 -> float/lane. Atomic-free.
template <int F>
__global__ __launch_bounds__(256) void k_agg(const float* __restrict__ xw,
                                             const float* __restrict__ dis,
                                             const int* __restrict__ rowptr,
                                             const int* __restrict__ csr,
                                             const float* __restrict__ bias,
                                             float* __restrict__ out, int n, int relu) {
    int wid = (blockIdx.x << 2) | (threadIdx.x >> 6);
    int lane = threadIdx.x & 63;
    if (wid >= n) return;
    float di = dis[wid];
    int beg = rowptr[wid], end = rowptr[wid + 1];
    if (F == 128) {
        const float2* xr = (const float2*)(xw + (size_t)wid * 128);
        float2 a = xr[lane];
        float sn = di * di;
        float ax = a.x * sn, ay = a.y * sn;
        for (int e = beg; e < end; ++e) {
            int s = csr[e];
            float nrm = di * dis[s];
            float2 v = ((const float2*)(xw + (size_t)s * 128))[lane];
            ax += nrm * v.x;
            ay += nrm * v.y;
        }
        ax += bias[2 * lane];
        ay += bias[2 * lane + 1];
        if (relu) { ax = fmaxf(ax, 0.f); ay = fmaxf(ay, 0.f); }
        ((float2*)(out + (size_t)wid * 128))[lane] = make_float2(ax, ay);
    } else {
        float a = xw[(size_t)wid * 64 + lane] * di * di;
        for (int e = beg; e < end; ++e) {
            int s = csr[e];
            a += di * dis[s] * xw[(size_t)s * 64 + lane];
        }
        a += bias[lane];
        if (relu) a = fmaxf(a, 0.f);
        out[(size_t)wid * 64 + lane] = a;
    }
}

extern "C" void kernel_launch(void* const* d_in, const int* in_sizes, int n_in,
                              void* d_out, int out_size, void* d_ws, size_t ws_size,
                              hipStream_t stream) {
    const float* x  = (const float*)d_in[0];
    const int*   ei = (const int*)d_in[1];
    const float* W1 = (const float*)d_in[2];
    const float* b1 = (const float*)d_in[3];
    const float* W2 = (const float*)d_in[4];
    const float* b2 = (const float*)d_in[5];
    float* out = (float*)d_out;

    const int n = in_sizes[0] / 128;   // 50000
    const int E = in_sizes[1] / 2;     // 800000
    const int* row = ei;
    const int* col = ei + E;

    char* ws = (char*)d_ws;
    size_t off = 0;
    auto alloc = [&](size_t bytes) -> void* {
        void* p = ws + off;
        off += (bytes + 255) & ~(size_t)255;
        return p;
    };
    int*   degcur = (int*)alloc((size_t)2 * n * 4);   // deg + cursor, zeroed together
    int*   deg    = degcur;
    int*   cursor = degcur + n;
    int*   rowptr = (int*)alloc((size_t)(n + 1) * 4);
    int*   csr    = (int*)alloc((size_t)E * 4);
    float* dis    = (float*)alloc((size_t)n * 4);
    float* xw1    = (float*)alloc((size_t)n * 128 * 4);
    float* h      = (float*)alloc((size_t)n * 128 * 4);
    float* xw2    = (float*)alloc((size_t)n * 64 * 4);
    (void)ws_size;

    k_zero_i32<<<(2 * n + 255) / 256, 256, 0, stream>>>(degcur, 2 * n);
    k_count<<<(E + 255) / 256, 256, 0, stream>>>(col, deg, E);
    k_dis<<<(n + 255) / 256, 256, 0, stream>>>(deg, dis, n);
    k_scan<<<1, 1024, 0, stream>>>(deg, rowptr, n);
    k_fill<<<(E + 255) / 256, 256, 0, stream>>>(row, col, rowptr, cursor, csr, E);

    dim3 g1((n + 31) / 32, 2);  // 128 output cols -> 2 col-tiles
    k_gemm<<<g1, 256, 0, stream>>>(x, W1, xw1, n, 128);
    k_agg<128><<<(n + 3) / 4, 256, 0, stream>>>(xw1, dis, rowptr, csr, b1, h, n, 1);

    dim3 g2((n + 31) / 32, 1);
    k_gemm<<<g2, 256, 0, stream>>>(h, W2, xw2, n, 64);
    k_agg<64><<<(n + 3) / 4, 256, 0, stream>>>(xw2, dis, rowptr, csr, b2, out, n, 0);
}

// Round 2
// 384.993 us; speedup vs baseline: 1.2164x; 1.2164x over previous
//
#include <hip/hip_runtime.h>
#include <hip/hip_fp16.h>

// GCN 2-layer. Pipeline: degree histogram -> rsqrt -> multi-block scan ->
// CSR fill -> [GEMM -> wave-per-node aggregate] x2.
// Key choices: transform-before-aggregate (64<=128 dims), atomic-free
// aggregation via CSR, fp16 storage for the gathered xw payload (halves
// random-gather bytes; accumulate fp32), no fp32 MFMA on CDNA4 so GEMM is
// vector-ALU LDS-tiled.

__global__ void k_count(const int* __restrict__ col, int* __restrict__ deg, int E) {
    int e = blockIdx.x * blockDim.x + threadIdx.x;
    if (e < E) atomicAdd(&deg[col[e]], 1);
}

__global__ void k_dis(const int* __restrict__ deg, float* __restrict__ dis, int n) {
    int i = blockIdx.x * blockDim.x + threadIdx.x;
    if (i < n) dis[i] = rsqrtf((float)deg[i] + 1.0f);  // +1 = self-loop
}

// Per-chunk inclusive scan: block b scans deg[b*1024 .. b*1024+1023] into
// rowptr[i+1] (no global offset yet), writes chunk total to bsum[b].
__global__ __launch_bounds__(1024) void k_scan_local(const int* __restrict__ deg,
                                                     int* __restrict__ rowptr,
                                                     int* __restrict__ bsum, int n) {
    __shared__ int s[1024];
    int b = blockIdx.x, tid = threadIdx.x;
    int i = b * 1024 + tid;
    int v = (i < n) ? deg[i] : 0;
    s[tid] = v;
    __syncthreads();
    for (int off = 1; off < 1024; off <<= 1) {
        int t = (tid >= off) ? s[tid - off] : 0;
        __syncthreads();
        s[tid] += t;
        __syncthreads();
    }
    if (i < n) rowptr[i + 1] = s[tid];
    if (tid == 1023) bsum[b] = s[1023];
    if (b == 0 && tid == 0) rowptr[0] = 0;
}

// Block b adds prefix(bsum[0..b)) to its chunk of rowptr. nb ~ 49, so the
// redundant per-block prefix recompute is trivial.
__global__ __launch_bounds__(256) void k_scan_fix(int* __restrict__ rowptr,
                                                  const int* __restrict__ bsum, int n) {
    __shared__ int red[256];
    int b = blockIdx.x, tid = threadIdx.x;
    int partial = 0;
    for (int j = tid; j < b; j += 256) partial += bsum[j];
    red[tid] = partial;
    __syncthreads();
    for (int off = 128; off > 0; off >>= 1) {
        if (tid < off) red[tid] += red[tid + off];
        __syncthreads();
    }
    int offv = red[0];
    if (offv == 0) return;
#pragma unroll
    for (int r = 0; r < 4; ++r) {
        int i = b * 1024 + r * 256 + tid;
        if (i < n) rowptr[i + 1] += offv;
    }
}

__global__ void k_fill(const int* __restrict__ row, const int* __restrict__ col,
                       const int* __restrict__ rowptr, int* __restrict__ cursor,
                       int* __restrict__ csr, int E) {
    int e = blockIdx.x * blockDim.x + threadIdx.x;
    if (e < E) {
        int c = col[e];
        int pos = atomicAdd(&cursor[c], 1);
        csr[rowptr[c] + pos] = row[e];
    }
}

// Y[M,Fw] = X[M,128] @ W[128,Fw]; tile BM=32 rows x BN=64 cols (blockIdx.y).
// Output type templated (fp16 for the aggregation payload).
template <typename T>
__global__ __launch_bounds__(256) void k_gemm(const float* __restrict__ X,
                                              const float* __restrict__ W,
                                              T* __restrict__ Y, int M, int Fw) {
    __shared__ float wsh[128 * 64];
    __shared__ float xsh[32 * 128];
    int tid = threadIdx.x;
    int m0 = blockIdx.x * 32;
    int n0 = blockIdx.y * 64;
    for (int i = tid; i < 128 * 16; i += 256) {
        int k = i >> 4, c4 = (i & 15) << 2;
        *(float4*)&wsh[k * 64 + c4] = *(const float4*)&W[(size_t)k * Fw + n0 + c4];
    }
    for (int i = tid; i < 32 * 32; i += 256) {
        int r = i >> 5, k4 = (i & 31) << 2;
        int m = m0 + r;
        float4 v = make_float4(0.f, 0.f, 0.f, 0.f);
        if (m < M) v = *(const float4*)&X[(size_t)m * 128 + k4];
        *(float4*)&xsh[r * 128 + k4] = v;
    }
    __syncthreads();
    int colq = tid & 31, rowq = tid >> 5;
    float acc[4][2] = {};
#pragma unroll 4
    for (int k = 0; k < 128; ++k) {
        float w0 = wsh[k * 64 + colq];
        float w1 = wsh[k * 64 + colq + 32];
#pragma unroll
        for (int r = 0; r < 4; ++r) {
            float xv = xsh[(rowq + 8 * r) * 128 + k];
            acc[r][0] += xv * w0;
            acc[r][1] += xv * w1;
        }
    }
#pragma unroll
    for (int r = 0; r < 4; ++r) {
        int m = m0 + rowq + 8 * r;
        if (m < M) {
            Y[(size_t)m * Fw + n0 + colq] = (T)acc[r][0];
            Y[(size_t)m * Fw + n0 + colq + 32] = (T)acc[r][1];
        }
    }
}

// One wave per node. xw payload is fp16 (256 B/edge at F=128, 128 B at F=64);
// accumulate fp32. Atomic-free via CSR.
template <int F>
__global__ __launch_bounds__(256) void k_agg(const __half* __restrict__ xw,
                                             const float* __restrict__ dis,
                                             const int* __restrict__ rowptr,
                                             const int* __restrict__ csr,
                                             const float* __restrict__ bias,
                                             float* __restrict__ out, int n, int relu) {
    int wid = (blockIdx.x << 2) | (threadIdx.x >> 6);
    int lane = threadIdx.x & 63;
    if (wid >= n) return;
    float di = dis[wid];
    int beg = rowptr[wid], end = rowptr[wid + 1];
    if (F == 128) {
        float2 a = __half22float2(((const __half2*)xw)[(size_t)wid * 64 + lane]);
        float sn = di * di;
        float ax = a.x * sn, ay = a.y * sn;
        for (int e = beg; e < end; ++e) {
            int s = csr[e];
            float nrm = di * dis[s];
            float2 v = __half22float2(((const __half2*)xw)[(size_t)s * 64 + lane]);
            ax += nrm * v.x;
            ay += nrm * v.y;
        }
        ax += bias[2 * lane];
        ay += bias[2 * lane + 1];
        if (relu) { ax = fmaxf(ax, 0.f); ay = fmaxf(ay, 0.f); }
        ((float2*)(out + (size_t)wid * 128))[lane] = make_float2(ax, ay);
    } else {
        float a = __half2float(xw[(size_t)wid * 64 + lane]) * di * di;
        for (int e = beg; e < end; ++e) {
            int s = csr[e];
            a += di * dis[s] * __half2float(xw[(size_t)s * 64 + lane]);
        }
        a += bias[lane];
        if (relu) a = fmaxf(a, 0.f);
        out[(size_t)wid * 64 + lane] = a;
    }
}

extern "C" void kernel_launch(void* const* d_in, const int* in_sizes, int n_in,
                              void* d_out, int out_size, void* d_ws, size_t ws_size,
                              hipStream_t stream) {
    const float* x  = (const float*)d_in[0];
    const int*   ei = (const int*)d_in[1];
    const float* W1 = (const float*)d_in[2];
    const float* b1 = (const float*)d_in[3];
    const float* W2 = (const float*)d_in[4];
    const float* b2 = (const float*)d_in[5];
    float* out = (float*)d_out;

    const int n = in_sizes[0] / 128;   // 50000
    const int E = in_sizes[1] / 2;     // 800000
    const int* row = ei;
    const int* col = ei + E;
    const int NB = (n + 1023) / 1024;

    char* ws = (char*)d_ws;
    size_t off = 0;
    auto alloc = [&](size_t bytes) -> void* {
        void* p = ws + off;
        off += (bytes + 255) & ~(size_t)255;
        return p;
    };
    int*    degcur = (int*)alloc((size_t)2 * n * 4);   // deg + cursor (zeroed together)
    int*    deg    = degcur;
    int*    cursor = degcur + n;
    int*    rowptr = (int*)alloc((size_t)(n + 1) * 4);
    int*    bsum   = (int*)alloc((size_t)NB * 4);
    int*    csr    = (int*)alloc((size_t)E * 4);
    float*  dis    = (float*)alloc((size_t)n * 4);
    __half* xw1    = (__half*)alloc((size_t)n * 128 * 2);
    float*  h      = (float*)alloc((size_t)n * 128 * 4);
    __half* xw2    = (__half*)alloc((size_t)n * 64 * 2);
    (void)ws_size;

    hipMemsetAsync(degcur, 0, (size_t)2 * n * 4, stream);
    k_count<<<(E + 255) / 256, 256, 0, stream>>>(col, deg, E);
    k_dis<<<(n + 255) / 256, 256, 0, stream>>>(deg, dis, n);
    k_scan_local<<<NB, 1024, 0, stream>>>(deg, rowptr, bsum, n);
    k_scan_fix<<<NB, 256, 0, stream>>>(rowptr, bsum, n);
    k_fill<<<(E + 255) / 256, 256, 0, stream>>>(row, col, rowptr, cursor, csr, E);

    dim3 g1((n + 31) / 32, 2);  // 128 output cols -> 2 col-tiles
    k_gemm<__half><<<g1, 256, 0, stream>>>(x, W1, xw1, n, 128);
    k_agg<128><<<(n + 3) / 4, 256, 0, stream>>>(xw1, dis, rowptr, csr, b1, h, n, 1);

    dim3 g2((n + 31) / 32, 1);
    k_gemm<__half><<<g2, 256, 0, stream>>>(h, W2, xw2, n, 64);
    k_agg<64><<<(n + 3) / 4, 256, 0, stream>>>(xw2, dis, rowptr, csr, b2, out, n, 0);
}

// Round 3
// 298.183 us; speedup vs baseline: 1.5705x; 1.2911x over previous
//
#include <hip/hip_runtime.h>
#include <hip/hip_fp16.h>

// GCN 2-layer. Pipeline: degree histogram -> rsqrt -> multi-block scan ->
// CSR fill -> [GEMM(scaled fp16 out) -> wave-per-node aggregate] x2.
// Aggregation identity: out[i] = dis[i]*(scaled[i] + sum_{j in N(i)} scaled[j]) + b,
// where scaled[j] = dis[j]*(x[j]@W) is produced by the GEMM epilogue (fp16).
// This removes dis[s] loads and multiplies from the gather loop; the loop is
// unrolled x8 for memory-level parallelism (latency-bound otherwise).

__global__ void k_count(const int* __restrict__ col, int* __restrict__ deg, int E) {
    int e = blockIdx.x * blockDim.x + threadIdx.x;
    if (e < E) atomicAdd(&deg[col[e]], 1);
}

__global__ void k_dis(const int* __restrict__ deg, float* __restrict__ dis, int n) {
    int i = blockIdx.x * blockDim.x + threadIdx.x;
    if (i < n) dis[i] = rsqrtf((float)deg[i] + 1.0f);  // +1 = self-loop
}

__global__ __launch_bounds__(1024) void k_scan_local(const int* __restrict__ deg,
                                                     int* __restrict__ rowptr,
                                                     int* __restrict__ bsum, int n) {
    __shared__ int s[1024];
    int b = blockIdx.x, tid = threadIdx.x;
    int i = b * 1024 + tid;
    int v = (i < n) ? deg[i] : 0;
    s[tid] = v;
    __syncthreads();
    for (int off = 1; off < 1024; off <<= 1) {
        int t = (tid >= off) ? s[tid - off] : 0;
        __syncthreads();
        s[tid] += t;
        __syncthreads();
    }
    if (i < n) rowptr[i + 1] = s[tid];
    if (tid == 1023) bsum[b] = s[1023];
    if (b == 0 && tid == 0) rowptr[0] = 0;
}

__global__ __launch_bounds__(256) void k_scan_fix(int* __restrict__ rowptr,
                                                  const int* __restrict__ bsum, int n) {
    __shared__ int red[256];
    int b = blockIdx.x, tid = threadIdx.x;
    int partial = 0;
    for (int j = tid; j < b; j += 256) partial += bsum[j];
    red[tid] = partial;
    __syncthreads();
    for (int off = 128; off > 0; off >>= 1) {
        if (tid < off) red[tid] += red[tid + off];
        __syncthreads();
    }
    int offv = red[0];
    if (offv == 0) return;
#pragma unroll
    for (int r = 0; r < 4; ++r) {
        int i = b * 1024 + r * 256 + tid;
        if (i < n) rowptr[i + 1] += offv;
    }
}

__global__ void k_fill(const int* __restrict__ row, const int* __restrict__ col,
                       const int* __restrict__ rowptr, int* __restrict__ cursor,
                       int* __restrict__ csr, int E) {
    int e = blockIdx.x * blockDim.x + threadIdx.x;
    if (e < E) {
        int c = col[e];
        int pos = atomicAdd(&cursor[c], 1);
        csr[rowptr[c] + pos] = row[e];
    }
}

// Y[M,Fw](fp16) = (X[M,128] @ W[128,Fw]) * scale[m], tile 64x64, 4x4 out/thread.
// k-step=4 with ds_read_b128 on both operands: per wave per step 8 b128 (~96cy)
// vs 64 FMA (128cy) -> compute-bound. xsh padded to 132 (16B-aligned, 2-way
// bank aliasing = free); wsh reads are lane-consecutive float4 (2-way = free).
__global__ __launch_bounds__(256) void k_gemm(const float* __restrict__ X,
                                              const float* __restrict__ W,
                                              const float* __restrict__ scale,
                                              __half* __restrict__ Y, int M, int Fw) {
    __shared__ float xsh[64 * 132];
    __shared__ float wsh[128 * 64];
    int tid = threadIdx.x;
    int m0 = blockIdx.x * 64;
    int n0 = blockIdx.y * 64;
    for (int i = tid; i < 128 * 16; i += 256) {
        int k = i >> 4, c4 = (i & 15) << 2;
        *(float4*)&wsh[k * 64 + c4] = *(const float4*)&W[(size_t)k * Fw + n0 + c4];
    }
    for (int i = tid; i < 64 * 32; i += 256) {
        int r = i >> 5, k4 = (i & 31) << 2;
        int m = m0 + r;
        float4 v = make_float4(0.f, 0.f, 0.f, 0.f);
        if (m < M) v = *(const float4*)&X[(size_t)m * 128 + k4];
        *(float4*)&xsh[r * 132 + k4] = v;
    }
    __syncthreads();
    int c4 = (tid & 15) << 2;
    int r4 = (tid >> 4) << 2;
    float acc[4][4] = {};
#pragma unroll 2
    for (int k = 0; k < 128; k += 4) {
        float4 xv[4], wv[4];
#pragma unroll
        for (int r = 0; r < 4; ++r) xv[r] = *(const float4*)&xsh[(r4 + r) * 132 + k];
#pragma unroll
        for (int kk = 0; kk < 4; ++kk) wv[kk] = *(const float4*)&wsh[(k + kk) * 64 + c4];
#pragma unroll
        for (int r = 0; r < 4; ++r) {
            acc[r][0] += xv[r].x * wv[0].x + xv[r].y * wv[1].x + xv[r].z * wv[2].x + xv[r].w * wv[3].x;
            acc[r][1] += xv[r].x * wv[0].y + xv[r].y * wv[1].y + xv[r].z * wv[2].y + xv[r].w * wv[3].y;
            acc[r][2] += xv[r].x * wv[0].z + xv[r].y * wv[1].z + xv[r].z * wv[2].z + xv[r].w * wv[3].z;
            acc[r][3] += xv[r].x * wv[0].w + xv[r].y * wv[1].w + xv[r].z * wv[2].w + xv[r].w * wv[3].w;
        }
    }
#pragma unroll
    for (int r = 0; r < 4; ++r) {
        int m = m0 + r4 + r;
        if (m < M) {
            float s = scale[m];
            __half2* dst = (__half2*)&Y[(size_t)m * Fw + n0 + c4];
            dst[0] = __floats2half2_rn(acc[r][0] * s, acc[r][1] * s);
            dst[1] = __floats2half2_rn(acc[r][2] * s, acc[r][3] * s);
        }
    }
}

// One wave per node; payload rows are pre-scaled by dis[src]. Edge loop
// unrolled x8: 8 independent index loads then 8 independent gathers in
// flight (latency-bound kernel; MLP is the lever, not bandwidth).
template <int F>
__global__ __launch_bounds__(256) void k_agg(const __half* __restrict__ xw,
                                             const float* __restrict__ dis,
                                             const int* __restrict__ rowptr,
                                             const int* __restrict__ csr,
                                             const float* __restrict__ bias,
                                             float* __restrict__ out, int n, int relu) {
    int wid = (blockIdx.x << 2) | (threadIdx.x >> 6);
    int lane = threadIdx.x & 63;
    if (wid >= n) return;
    float di = dis[wid];
    int beg = rowptr[wid], end = rowptr[wid + 1];
    if (F == 128) {
        const __half2* xh = (const __half2*)xw;
        float2 sf = __half22float2(xh[(size_t)wid * 64 + lane]);
        float ax = sf.x, ay = sf.y;
        int e = beg;
        for (; e + 8 <= end; e += 8) {
            int s0 = csr[e], s1 = csr[e + 1], s2 = csr[e + 2], s3 = csr[e + 3];
            int s4 = csr[e + 4], s5 = csr[e + 5], s6 = csr[e + 6], s7 = csr[e + 7];
            __half2 v0 = xh[(size_t)s0 * 64 + lane];
            __half2 v1 = xh[(size_t)s1 * 64 + lane];
            __half2 v2 = xh[(size_t)s2 * 64 + lane];
            __half2 v3 = xh[(size_t)s3 * 64 + lane];
            __half2 v4 = xh[(size_t)s4 * 64 + lane];
            __half2 v5 = xh[(size_t)s5 * 64 + lane];
            __half2 v6 = xh[(size_t)s6 * 64 + lane];
            __half2 v7 = xh[(size_t)s7 * 64 + lane];
            float2 f0 = __half22float2(v0), f1 = __half22float2(v1);
            float2 f2 = __half22float2(v2), f3 = __half22float2(v3);
            float2 f4 = __half22float2(v4), f5 = __half22float2(v5);
            float2 f6 = __half22float2(v6), f7 = __half22float2(v7);
            ax += (f0.x + f1.x) + (f2.x + f3.x) + (f4.x + f5.x) + (f6.x + f7.x);
            ay += (f0.y + f1.y) + (f2.y + f3.y) + (f4.y + f5.y) + (f6.y + f7.y);
        }
        for (; e < end; ++e) {
            float2 f = __half22float2(xh[(size_t)csr[e] * 64 + lane]);
            ax += f.x;
            ay += f.y;
        }
        ax = ax * di + bias[2 * lane];
        ay = ay * di + bias[2 * lane + 1];
        if (relu) { ax = fmaxf(ax, 0.f); ay = fmaxf(ay, 0.f); }
        ((float2*)(out + (size_t)wid * 128))[lane] = make_float2(ax, ay);
    } else {
        float a = __half2float(xw[(size_t)wid * 64 + lane]);
        int e = beg;
        for (; e + 8 <= end; e += 8) {
            int s0 = csr[e], s1 = csr[e + 1], s2 = csr[e + 2], s3 = csr[e + 3];
            int s4 = csr[e + 4], s5 = csr[e + 5], s6 = csr[e + 6], s7 = csr[e + 7];
            float f0 = __half2float(xw[(size_t)s0 * 64 + lane]);
            float f1 = __half2float(xw[(size_t)s1 * 64 + lane]);
            float f2 = __half2float(xw[(size_t)s2 * 64 + lane]);
            float f3 = __half2float(xw[(size_t)s3 * 64 + lane]);
            float f4 = __half2float(xw[(size_t)s4 * 64 + lane]);
            float f5 = __half2float(xw[(size_t)s5 * 64 + lane]);
            float f6 = __half2float(xw[(size_t)s6 * 64 + lane]);
            float f7 = __half2float(xw[(size_t)s7 * 64 + lane]);
            a += (f0 + f1) + (f2 + f3) + (f4 + f5) + (f6 + f7);
        }
        for (; e < end; ++e) a += __half2float(xw[(size_t)csr[e] * 64 + lane]);
        a = a * di + bias[lane];
        if (relu) a = fmaxf(a, 0.f);
        out[(size_t)wid * 64 + lane] = a;
    }
}

extern "C" void kernel_launch(void* const* d_in, const int* in_sizes, int n_in,
                              void* d_out, int out_size, void* d_ws, size_t ws_size,
                              hipStream_t stream) {
    const float* x  = (const float*)d_in[0];
    const int*   ei = (const int*)d_in[1];
    const float* W1 = (const float*)d_in[2];
    const float* b1 = (const float*)d_in[3];
    const float* W2 = (const float*)d_in[4];
    const float* b2 = (const float*)d_in[5];
    float* out = (float*)d_out;

    const int n = in_sizes[0] / 128;   // 50000
    const int E = in_sizes[1] / 2;     // 800000
    const int* row = ei;
    const int* col = ei + E;
    const int NB = (n + 1023) / 1024;

    char* ws = (char*)d_ws;
    size_t off = 0;
    auto alloc = [&](size_t bytes) -> void* {
        void* p = ws + off;
        off += (bytes + 255) & ~(size_t)255;
        return p;
    };
    int*    degcur = (int*)alloc((size_t)2 * n * 4);   // deg + cursor (zeroed together)
    int*    deg    = degcur;
    int*    cursor = degcur + n;
    int*    rowptr = (int*)alloc((size_t)(n + 1) * 4);
    int*    bsum   = (int*)alloc((size_t)NB * 4);
    int*    csr    = (int*)alloc((size_t)E * 4);
    float*  dis    = (float*)alloc((size_t)n * 4);
    __half* xw1    = (__half*)alloc((size_t)n * 128 * 2);
    float*  h      = (float*)alloc((size_t)n * 128 * 4);
    __half* xw2    = (__half*)alloc((size_t)n * 64 * 2);
    (void)ws_size;

    hipMemsetAsync(degcur, 0, (size_t)2 * n * 4, stream);
    k_count<<<(E + 255) / 256, 256, 0, stream>>>(col, deg, E);
    k_dis<<<(n + 255) / 256, 256, 0, stream>>>(deg, dis, n);
    k_scan_local<<<NB, 1024, 0, stream>>>(deg, rowptr, bsum, n);
    k_scan_fix<<<NB, 256, 0, stream>>>(rowptr, bsum, n);
    k_fill<<<(E + 255) / 256, 256, 0, stream>>>(row, col, rowptr, cursor, csr, E);

    dim3 g1((n + 63) / 64, 2);  // 128 output cols -> 2 col-tiles of 64
    k_gemm<<<g1, 256, 0, stream>>>(x, W1, dis, xw1, n, 128);
    k_agg<128><<<(n + 3) / 4, 256, 0, stream>>>(xw1, dis, rowptr, csr, b1, h, n, 1);

    dim3 g2((n + 63) / 64, 1);
    k_gemm<<<g2, 256, 0, stream>>>(h, W2, dis, xw2, n, 64);
    k_agg<64><<<(n + 3) / 4, 256, 0, stream>>>(xw2, dis, rowptr, csr, b2, out, n, 0);
}

// Round 4
// 267.173 us; speedup vs baseline: 1.7528x; 1.1161x over previous
//
#include <hip/hip_runtime.h>
#include <hip/hip_fp16.h>

// GCN 2-layer. degree histogram -> rsqrt -> multi-block scan -> CSR fill ->
// [MFMA fp16 GEMM (scaled fp16 out) -> wave-per-node aggregate] x2.
// out[i] = dis[i]*(scaled[i] + sum_{j in N(i)} scaled[j]) + b, with
// scaled[j] = dis[j]*(x[j]@W) written fp16 by the GEMM epilogue.
// GEMM uses v_mfma_f32_16x16x32_f16 (fp32 matmul has no MFMA on CDNA4; the
// fp16 accuracy budget is already spent on the gather payload). W lives in
// LDS transposed [n][k] with XOR-swizzled 16B blocks (<=2-way banks = free);
// A-frags (8 contiguous k elems) load directly from global.

typedef _Float16 half8 __attribute__((ext_vector_type(8)));
typedef float floatx4 __attribute__((ext_vector_type(4)));

__global__ void k_count(const int* __restrict__ col, int* __restrict__ deg, int E) {
    int e = blockIdx.x * blockDim.x + threadIdx.x;
    if (e < E) atomicAdd(&deg[col[e]], 1);
}

__global__ void k_dis(const int* __restrict__ deg, float* __restrict__ dis, int n) {
    int i = blockIdx.x * blockDim.x + threadIdx.x;
    if (i < n) dis[i] = rsqrtf((float)deg[i] + 1.0f);  // +1 = self-loop
}

__global__ __launch_bounds__(1024) void k_scan_local(const int* __restrict__ deg,
                                                     int* __restrict__ rowptr,
                                                     int* __restrict__ bsum, int n) {
    __shared__ int s[1024];
    int b = blockIdx.x, tid = threadIdx.x;
    int i = b * 1024 + tid;
    int v = (i < n) ? deg[i] : 0;
    s[tid] = v;
    __syncthreads();
    for (int off = 1; off < 1024; off <<= 1) {
        int t = (tid >= off) ? s[tid - off] : 0;
        __syncthreads();
        s[tid] += t;
        __syncthreads();
    }
    if (i < n) rowptr[i + 1] = s[tid];
    if (tid == 1023) bsum[b] = s[1023];
    if (b == 0 && tid == 0) rowptr[0] = 0;
}

__global__ __launch_bounds__(256) void k_scan_fix(int* __restrict__ rowptr,
                                                  const int* __restrict__ bsum, int n) {
    __shared__ int red[256];
    int b = blockIdx.x, tid = threadIdx.x;
    int partial = 0;
    for (int j = tid; j < b; j += 256) partial += bsum[j];
    red[tid] = partial;
    __syncthreads();
    for (int off = 128; off > 0; off >>= 1) {
        if (tid < off) red[tid] += red[tid + off];
        __syncthreads();
    }
    int offv = red[0];
    if (offv == 0) return;
#pragma unroll
    for (int r = 0; r < 4; ++r) {
        int i = b * 1024 + r * 256 + tid;
        if (i < n) rowptr[i + 1] += offv;
    }
}

__global__ void k_fill(const int* __restrict__ row, const int* __restrict__ col,
                       const int* __restrict__ rowptr, int* __restrict__ cursor,
                       int* __restrict__ csr, int E) {
    int e = blockIdx.x * blockDim.x + threadIdx.x;
    if (e < E) {
        int c = col[e];
        int pos = atomicAdd(&cursor[c], 1);
        csr[rowptr[c] + pos] = row[e];
    }
}

// Y[M,N](fp16) = (X[M,128] @ W[128,N]) * scale[m].
// Block: 64 rows (4 waves x 16), all N cols. K=128 in 4 MFMA steps of 32.
// LDS: Wt[n][k] fp16, stored as half2 dwords; 16B block at (n,kblk) lives at
// dword n*64 + (kblk ^ (n&15))*4  (kblk = k/8). XOR swizzle -> <=2-way banks
// for both the staging writes and the ds_read_b128 B-frag reads.
// Frag layouts (verified m89/m118/m120): A[m=lane&15][k=quad*8+j],
// B[k=quad*8+j][n=lane&15], D row=quad*4+reg, col=lane&15.
template <int N, typename AT>
__global__ __launch_bounds__(256) void k_gemm_mfma(const AT* __restrict__ X,
                                                   const float* __restrict__ W,
                                                   const float* __restrict__ scale,
                                                   __half* __restrict__ Y, int M) {
    __shared__ __align__(16) __half2 wt[N * 64];
    int tid = threadIdx.x;
    for (int i = tid; i < N * 64; i += 256) {
        int n = i & (N - 1);
        int k2 = i / N;  // k = 2*k2
        float w0 = W[(size_t)(2 * k2) * N + n];
        float w1 = W[(size_t)(2 * k2 + 1) * N + n];
        wt[n * 64 + ((k2 >> 2) ^ (n & 15)) * 4 + (k2 & 3)] = __floats2half2_rn(w0, w1);
    }
    __syncthreads();

    int wid = tid >> 6, lane = tid & 63;
    int col = lane & 15, quad = lane >> 4;
    int m_a = blockIdx.x * 64 + wid * 16 + col;  // this lane's A-frag row
    bool a_ok = m_a < M;
    constexpr int NT = N / 16;
    floatx4 acc[NT] = {};
#pragma unroll
    for (int ks = 0; ks < 4; ++ks) {
        int k = ks * 32 + quad * 8;
        half8 af;
        if constexpr (sizeof(AT) == 4) {  // fp32 input, convert in regs
            floatx4 a0 = {0.f, 0.f, 0.f, 0.f}, a1 = {0.f, 0.f, 0.f, 0.f};
            if (a_ok) {
                a0 = *(const floatx4*)&X[(size_t)m_a * 128 + k];
                a1 = *(const floatx4*)&X[(size_t)m_a * 128 + k + 4];
            }
            af = half8{(_Float16)a0[0], (_Float16)a0[1], (_Float16)a0[2], (_Float16)a0[3],
                       (_Float16)a1[0], (_Float16)a1[1], (_Float16)a1[2], (_Float16)a1[3]};
        } else {  // fp16 input: one 16B load
            half8 t = {};
            if (a_ok) t = *(const half8*)(const void*)&X[(size_t)m_a * 128 + k];
            af = t;
        }
        int kblk = ks * 4 + quad;
#pragma unroll
        for (int nt = 0; nt < NT; ++nt) {
            int n = nt * 16 + col;
            half8 bf = *(const half8*)(const void*)&wt[n * 64 + (kblk ^ (n & 15)) * 4];
            acc[nt] = __builtin_amdgcn_mfma_f32_16x16x32_f16(af, bf, acc[nt], 0, 0, 0);
        }
    }
    int mbase = blockIdx.x * 64 + wid * 16 + quad * 4;
    float s[4];
#pragma unroll
    for (int r = 0; r < 4; ++r) s[r] = (mbase + r < M) ? scale[mbase + r] : 0.f;
#pragma unroll
    for (int nt = 0; nt < NT; ++nt) {
#pragma unroll
        for (int r = 0; r < 4; ++r) {
            if (mbase + r < M)
                Y[(size_t)(mbase + r) * N + nt * 16 + col] = __float2half(acc[nt][r] * s[r]);
        }
    }
}

// One wave per node; payload rows pre-scaled by dis[src]. Edge loop unrolled
// x8 for MLP (latency-bound). OT=__half for hidden layer, float for output.
template <int F, typename OT>
__global__ __launch_bounds__(256) void k_agg(const __half* __restrict__ xw,
                                             const float* __restrict__ dis,
                                             const int* __restrict__ rowptr,
                                             const int* __restrict__ csr,
                                             const float* __restrict__ bias,
                                             OT* __restrict__ out, int n, int relu) {
    int wid = (blockIdx.x << 2) | (threadIdx.x >> 6);
    int lane = threadIdx.x & 63;
    if (wid >= n) return;
    float di = dis[wid];
    int beg = rowptr[wid], end = rowptr[wid + 1];
    if (F == 128) {
        const __half2* xh = (const __half2*)xw;
        float2 sf = __half22float2(xh[(size_t)wid * 64 + lane]);
        float ax = sf.x, ay = sf.y;
        int e = beg;
        for (; e + 8 <= end; e += 8) {
            int s0 = csr[e], s1 = csr[e + 1], s2 = csr[e + 2], s3 = csr[e + 3];
            int s4 = csr[e + 4], s5 = csr[e + 5], s6 = csr[e + 6], s7 = csr[e + 7];
            float2 f0 = __half22float2(xh[(size_t)s0 * 64 + lane]);
            float2 f1 = __half22float2(xh[(size_t)s1 * 64 + lane]);
            float2 f2 = __half22float2(xh[(size_t)s2 * 64 + lane]);
            float2 f3 = __half22float2(xh[(size_t)s3 * 64 + lane]);
            float2 f4 = __half22float2(xh[(size_t)s4 * 64 + lane]);
            float2 f5 = __half22float2(xh[(size_t)s5 * 64 + lane]);
            float2 f6 = __half22float2(xh[(size_t)s6 * 64 + lane]);
            float2 f7 = __half22float2(xh[(size_t)s7 * 64 + lane]);
            ax += (f0.x + f1.x) + (f2.x + f3.x) + (f4.x + f5.x) + (f6.x + f7.x);
            ay += (f0.y + f1.y) + (f2.y + f3.y) + (f4.y + f5.y) + (f6.y + f7.y);
        }
        for (; e < end; ++e) {
            float2 f = __half22float2(xh[(size_t)csr[e] * 64 + lane]);
            ax += f.x;
            ay += f.y;
        }
        ax = ax * di + bias[2 * lane];
        ay = ay * di + bias[2 * lane + 1];
        if (relu) { ax = fmaxf(ax, 0.f); ay = fmaxf(ay, 0.f); }
        if constexpr (sizeof(OT) == 2)
            ((__half2*)out)[(size_t)wid * 64 + lane] = __floats2half2_rn(ax, ay);
        else
            ((float2*)(void*)out)[(size_t)wid * 64 + lane] = make_float2(ax, ay);
    } else {
        float a = __half2float(xw[(size_t)wid * 64 + lane]);
        int e = beg;
        for (; e + 8 <= end; e += 8) {
            int s0 = csr[e], s1 = csr[e + 1], s2 = csr[e + 2], s3 = csr[e + 3];
            int s4 = csr[e + 4], s5 = csr[e + 5], s6 = csr[e + 6], s7 = csr[e + 7];
            float f0 = __half2float(xw[(size_t)s0 * 64 + lane]);
            float f1 = __half2float(xw[(size_t)s1 * 64 + lane]);
            float f2 = __half2float(xw[(size_t)s2 * 64 + lane]);
            float f3 = __half2float(xw[(size_t)s3 * 64 + lane]);
            float f4 = __half2float(xw[(size_t)s4 * 64 + lane]);
            float f5 = __half2float(xw[(size_t)s5 * 64 + lane]);
            float f6 = __half2float(xw[(size_t)s6 * 64 + lane]);
            float f7 = __half2float(xw[(size_t)s7 * 64 + lane]);
            a += (f0 + f1) + (f2 + f3) + (f4 + f5) + (f6 + f7);
        }
        for (; e < end; ++e) a += __half2float(xw[(size_t)csr[e] * 64 + lane]);
        a = a * di + bias[lane];
        if (relu) a = fmaxf(a, 0.f);
        ((float*)(void*)out)[(size_t)wid * 64 + lane] = a;
    }
}

extern "C" void kernel_launch(void* const* d_in, const int* in_sizes, int n_in,
                              void* d_out, int out_size, void* d_ws, size_t ws_size,
                              hipStream_t stream) {
    const float* x  = (const float*)d_in[0];
    const int*   ei = (const int*)d_in[1];
    const float* W1 = (const float*)d_in[2];
    const float* b1 = (const float*)d_in[3];
    const float* W2 = (const float*)d_in[4];
    const float* b2 = (const float*)d_in[5];
    float* out = (float*)d_out;

    const int n = in_sizes[0] / 128;   // 50000
    const int E = in_sizes[1] / 2;     // 800000
    const int* row = ei;
    const int* col = ei + E;
    const int NB = (n + 1023) / 1024;

    char* ws = (char*)d_ws;
    size_t off = 0;
    auto alloc = [&](size_t bytes) -> void* {
        void* p = ws + off;
        off += (bytes + 255) & ~(size_t)255;
        return p;
    };
    int*    degcur = (int*)alloc((size_t)2 * n * 4);   // deg + cursor (zeroed together)
    int*    deg    = degcur;
    int*    cursor = degcur + n;
    int*    rowptr = (int*)alloc((size_t)(n + 1) * 4);
    int*    bsum   = (int*)alloc((size_t)NB * 4);
    int*    csr    = (int*)alloc((size_t)E * 4);
    float*  dis    = (float*)alloc((size_t)n * 4);
    __half* xw1    = (__half*)alloc((size_t)n * 128 * 2);
    __half* h      = (__half*)alloc((size_t)n * 128 * 2);
    __half* xw2    = (__half*)alloc((size_t)n * 64 * 2);
    (void)ws_size;

    hipMemsetAsync(degcur, 0, (size_t)2 * n * 4, stream);
    k_count<<<(E + 255) / 256, 256, 0, stream>>>(col, deg, E);
    k_dis<<<(n + 255) / 256, 256, 0, stream>>>(deg, dis, n);
    k_scan_local<<<NB, 1024, 0, stream>>>(deg, rowptr, bsum, n);
    k_scan_fix<<<NB, 256, 0, stream>>>(rowptr, bsum, n);
    k_fill<<<(E + 255) / 256, 256, 0, stream>>>(row, col, rowptr, cursor, csr, E);

    int gb = (n + 63) / 64;
    k_gemm_mfma<128, float><<<gb, 256, 0, stream>>>(x, W1, dis, xw1, n);
    k_agg<128, __half><<<(n + 3) / 4, 256, 0, stream>>>(xw1, dis, rowptr, csr, b1, h, n, 1);

    k_gemm_mfma<64, __half><<<gb, 256, 0, stream>>>(h, W2, dis, xw2, n);
    k_agg<64, float><<<(n + 3) / 4, 256, 0, stream>>>(xw2, dis, rowptr, csr, b2, out, n, 0);
}

// Round 5
// 233.306 us; speedup vs baseline: 2.0073x; 1.1452x over previous
//
#include <hip/hip_runtime.h>
#include <hip/hip_fp16.h>

// GCN 2-layer. degree histogram (+edge rank) -> rsqrt -> multi-block scan ->
// atomic-free CSR fill -> [MFMA fp16 GEMM (scaled fp16 out) -> aggregate] x2.
// out[i] = dis[i]*(scaled[i] + sum_{j in N(i)} scaled[j]) + b, with
// scaled[j] = dis[j]*(x[j]@W) written fp16 by the GEMM epilogue.
// k_count captures atomicAdd's return as the edge's rank within its target,
// so k_fill has no atomic and no dependent chain (was 44us latency-bound).

typedef _Float16 half8 __attribute__((ext_vector_type(8)));
typedef float floatx4 __attribute__((ext_vector_type(4)));

__global__ void k_count(const int* __restrict__ col, int* __restrict__ deg,
                        int* __restrict__ rank, int E) {
    int e = blockIdx.x * blockDim.x + threadIdx.x;
    if (e < E) rank[e] = atomicAdd(&deg[col[e]], 1);
}

__global__ void k_dis(const int* __restrict__ deg, float* __restrict__ dis, int n) {
    int i = blockIdx.x * blockDim.x + threadIdx.x;
    if (i < n) dis[i] = rsqrtf((float)deg[i] + 1.0f);  // +1 = self-loop
}

__global__ __launch_bounds__(1024) void k_scan_local(const int* __restrict__ deg,
                                                     int* __restrict__ rowptr,
                                                     int* __restrict__ bsum, int n) {
    __shared__ int s[1024];
    int b = blockIdx.x, tid = threadIdx.x;
    int i = b * 1024 + tid;
    int v = (i < n) ? deg[i] : 0;
    s[tid] = v;
    __syncthreads();
    for (int off = 1; off < 1024; off <<= 1) {
        int t = (tid >= off) ? s[tid - off] : 0;
        __syncthreads();
        s[tid] += t;
        __syncthreads();
    }
    if (i < n) rowptr[i + 1] = s[tid];
    if (tid == 1023) bsum[b] = s[1023];
    if (b == 0 && tid == 0) rowptr[0] = 0;
}

__global__ __launch_bounds__(256) void k_scan_fix(int* __restrict__ rowptr,
                                                  const int* __restrict__ bsum, int n) {
    __shared__ int red[256];
    int b = blockIdx.x, tid = threadIdx.x;
    int partial = 0;
    for (int j = tid; j < b; j += 256) partial += bsum[j];
    red[tid] = partial;
    __syncthreads();
    for (int off = 128; off > 0; off >>= 1) {
        if (tid < off) red[tid] += red[tid + off];
        __syncthreads();
    }
    int offv = red[0];
    if (offv == 0) return;
#pragma unroll
    for (int r = 0; r < 4; ++r) {
        int i = b * 1024 + r * 256 + tid;
        if (i < n) rowptr[i + 1] += offv;
    }
}

// Atomic-free: position = rowptr[target] + precomputed rank.
__global__ void k_fill(const int* __restrict__ row, const int* __restrict__ col,
                       const int* __restrict__ rowptr, const int* __restrict__ rank,
                       int* __restrict__ csr, int E) {
    int e = blockIdx.x * blockDim.x + threadIdx.x;
    if (e < E) csr[rowptr[col[e]] + rank[e]] = row[e];
}

// Y[M,N](fp16) = (X[M,128] @ W[128,N]) * scale[m].
// Block: 64 rows (4 waves x 16), all N cols. K=128 in 4 MFMA steps of 32.
// LDS: Wt[n][k] fp16 as half2 dwords; 16B block (n,kblk) at dword
// n*64 + (kblk ^ (n&15))*4. XOR swizzle -> <=2-way banks (free) for both
// staging writes and ds_read_b128 B-frag reads.
// Frags (m89/m118/m120): A[m=lane&15][k=quad*8+j], B[k=quad*8+j][n=lane&15],
// D row=quad*4+reg, col=lane&15.
template <int N, typename AT>
__global__ __launch_bounds__(256) void k_gemm_mfma(const AT* __restrict__ X,
                                                   const float* __restrict__ W,
                                                   const float* __restrict__ scale,
                                                   __half* __restrict__ Y, int M) {
    __shared__ __align__(16) __half2 wt[N * 64];
    int tid = threadIdx.x;
    for (int i = tid; i < N * 64; i += 256) {
        int n = i & (N - 1);
        int k2 = i / N;  // k = 2*k2
        float w0 = W[(size_t)(2 * k2) * N + n];
        float w1 = W[(size_t)(2 * k2 + 1) * N + n];
        wt[n * 64 + ((k2 >> 2) ^ (n & 15)) * 4 + (k2 & 3)] = __floats2half2_rn(w0, w1);
    }
    __syncthreads();

    int wid = tid >> 6, lane = tid & 63;
    int col = lane & 15, quad = lane >> 4;
    int m_a = blockIdx.x * 64 + wid * 16 + col;
    bool a_ok = m_a < M;
    constexpr int NT = N / 16;
    floatx4 acc[NT] = {};
#pragma unroll
    for (int ks = 0; ks < 4; ++ks) {
        int k = ks * 32 + quad * 8;
        half8 af;
        if constexpr (sizeof(AT) == 4) {
            floatx4 a0 = {0.f, 0.f, 0.f, 0.f}, a1 = {0.f, 0.f, 0.f, 0.f};
            if (a_ok) {
                a0 = *(const floatx4*)&X[(size_t)m_a * 128 + k];
                a1 = *(const floatx4*)&X[(size_t)m_a * 128 + k + 4];
            }
            af = half8{(_Float16)a0[0], (_Float16)a0[1], (_Float16)a0[2], (_Float16)a0[3],
                       (_Float16)a1[0], (_Float16)a1[1], (_Float16)a1[2], (_Float16)a1[3]};
        } else {
            half8 t = {};
            if (a_ok) t = *(const half8*)(const void*)&X[(size_t)m_a * 128 + k];
            af = t;
        }
        int kblk = ks * 4 + quad;
#pragma unroll
        for (int nt = 0; nt < NT; ++nt) {
            int n = nt * 16 + col;
            half8 bf = *(const half8*)(const void*)&wt[n * 64 + (kblk ^ (n & 15)) * 4];
            acc[nt] = __builtin_amdgcn_mfma_f32_16x16x32_f16(af, bf, acc[nt], 0, 0, 0);
        }
    }
    int mbase = blockIdx.x * 64 + wid * 16 + quad * 4;
    float s[4];
#pragma unroll
    for (int r = 0; r < 4; ++r) s[r] = (mbase + r < M) ? scale[mbase + r] : 0.f;
#pragma unroll
    for (int nt = 0; nt < NT; ++nt) {
#pragma unroll
        for (int r = 0; r < 4; ++r) {
            if (mbase + r < M)
                Y[(size_t)(mbase + r) * N + nt * 16 + col] = __float2half(acc[nt][r] * s[r]);
        }
    }
}

// F=128: one wave/node, float2/lane, edge loop unrolled x16 then x4 (MLP).
__global__ __launch_bounds__(256) void k_agg128(const __half* __restrict__ xw,
                                                const float* __restrict__ dis,
                                                const int* __restrict__ rowptr,
                                                const int* __restrict__ csr,
                                                const float* __restrict__ bias,
                                                __half* __restrict__ out, int n) {
    int wid = (blockIdx.x << 2) | (threadIdx.x >> 6);
    int lane = threadIdx.x & 63;
    if (wid >= n) return;
    float di = dis[wid];
    int beg = rowptr[wid], end = rowptr[wid + 1];
    const __half2* xh = (const __half2*)xw;
    float2 sf = __half22float2(xh[(size_t)wid * 64 + lane]);
    float ax = sf.x, ay = sf.y;
    int e = beg;
    for (; e + 16 <= end; e += 16) {
        int s[16];
        float2 v[16];
#pragma unroll
        for (int j = 0; j < 16; ++j) s[j] = csr[e + j];
#pragma unroll
        for (int j = 0; j < 16; ++j) v[j] = __half22float2(xh[(size_t)s[j] * 64 + lane]);
#pragma unroll
        for (int j = 0; j < 16; ++j) { ax += v[j].x; ay += v[j].y; }
    }
    for (; e + 4 <= end; e += 4) {
        int s[4];
        float2 v[4];
#pragma unroll
        for (int j = 0; j < 4; ++j) s[j] = csr[e + j];
#pragma unroll
        for (int j = 0; j < 4; ++j) v[j] = __half22float2(xh[(size_t)s[j] * 64 + lane]);
#pragma unroll
        for (int j = 0; j < 4; ++j) { ax += v[j].x; ay += v[j].y; }
    }
    for (; e < end; ++e) {
        float2 f = __half22float2(xh[(size_t)csr[e] * 64 + lane]);
        ax += f.x;
        ay += f.y;
    }
    float2 bb = ((const float2*)bias)[lane];
    ax = fmaxf(ax * di + bb.x, 0.f);
    ay = fmaxf(ay * di + bb.y, 0.f);
    ((__half2*)out)[(size_t)wid * 64 + lane] = __floats2half2_rn(ax, ay);
}

// F=64: TWO nodes per wave (half-wave each; 32 lanes x half2 = 128B row).
// Loop bound = pairwise max degree; out-of-range edges predicated to row 0.
__global__ __launch_bounds__(256) void k_agg64(const __half* __restrict__ xw,
                                               const float* __restrict__ dis,
                                               const int* __restrict__ rowptr,
                                               const int* __restrict__ csr,
                                               const float* __restrict__ bias,
                                               float* __restrict__ out, int n) {
    int tid = threadIdx.x;
    int lane = tid & 63, hl = lane & 31;
    int node = blockIdx.x * 8 + ((tid >> 6) << 1) + (lane >> 5);
    float di = 0.f;
    int beg = 0, end = 0;
    if (node < n) {
        di = dis[node];
        beg = rowptr[node];
        end = rowptr[node + 1];
    }
    int deg = end - beg;
    int mx = max(deg, __shfl(deg, lane ^ 32));
    const __half2* xh = (const __half2*)xw;
    float2 a = make_float2(0.f, 0.f);
    if (node < n) a = __half22float2(xh[(size_t)node * 32 + hl]);
    int i = 0;
    for (; i + 8 <= mx; i += 8) {
        int s[8];
        float2 v[8];
#pragma unroll
        for (int j = 0; j < 8; ++j) {
            int e = beg + i + j;
            s[j] = (e < end) ? csr[e] : 0;
        }
#pragma unroll
        for (int j = 0; j < 8; ++j) v[j] = __half22float2(xh[(size_t)s[j] * 32 + hl]);
#pragma unroll
        for (int j = 0; j < 8; ++j) {
            if (beg + i + j < end) { a.x += v[j].x; a.y += v[j].y; }
        }
    }
    for (; i < mx; ++i) {
        int e = beg + i;
        int s = (e < end) ? csr[e] : 0;
        float2 v = __half22float2(xh[(size_t)s * 32 + hl]);
        if (e < end) { a.x += v.x; a.y += v.y; }
    }
    if (node < n) {
        float2 bb = ((const float2*)bias)[hl];
        ((float2*)out)[(size_t)node * 32 + hl] =
            make_float2(a.x * di + bb.x, a.y * di + bb.y);
    }
}

extern "C" void kernel_launch(void* const* d_in, const int* in_sizes, int n_in,
                              void* d_out, int out_size, void* d_ws, size_t ws_size,
                              hipStream_t stream) {
    const float* x  = (const float*)d_in[0];
    const int*   ei = (const int*)d_in[1];
    const float* W1 = (const float*)d_in[2];
    const float* b1 = (const float*)d_in[3];
    const float* W2 = (const float*)d_in[4];
    const float* b2 = (const float*)d_in[5];
    float* out = (float*)d_out;

    const int n = in_sizes[0] / 128;   // 50000
    const int E = in_sizes[1] / 2;     // 800000
    const int* row = ei;
    const int* col = ei + E;
    const int NB = (n + 1023) / 1024;

    char* ws = (char*)d_ws;
    size_t off = 0;
    auto alloc = [&](size_t bytes) -> void* {
        void* p = ws + off;
        off += (bytes + 255) & ~(size_t)255;
        return p;
    };
    int*    deg    = (int*)alloc((size_t)n * 4);
    int*    rowptr = (int*)alloc((size_t)(n + 1) * 4);
    int*    bsum   = (int*)alloc((size_t)NB * 4);
    int*    rank   = (int*)alloc((size_t)E * 4);
    int*    csr    = (int*)alloc((size_t)E * 4);
    float*  dis    = (float*)alloc((size_t)n * 4);
    __half* xw1    = (__half*)alloc((size_t)n * 128 * 2);
    __half* h      = (__half*)alloc((size_t)n * 128 * 2);
    __half* xw2    = (__half*)alloc((size_t)n * 64 * 2);
    (void)ws_size;

    hipMemsetAsync(deg, 0, (size_t)n * 4, stream);
    k_count<<<(E + 255) / 256, 256, 0, stream>>>(col, deg, rank, E);
    k_dis<<<(n + 255) / 256, 256, 0, stream>>>(deg, dis, n);
    k_scan_local<<<NB, 1024, 0, stream>>>(deg, rowptr, bsum, n);
    k_scan_fix<<<NB, 256, 0, stream>>>(rowptr, bsum, n);
    k_fill<<<(E + 255) / 256, 256, 0, stream>>>(row, col, rowptr, rank, csr, E);

    int gb = (n + 63) / 64;
    k_gemm_mfma<128, float><<<gb, 256, 0, stream>>>(x, W1, dis, xw1, n);
    k_agg128<<<(n + 3) / 4, 256, 0, stream>>>(xw1, dis, rowptr, csr, b1, h, n);

    k_gemm_mfma<64, __half><<<gb, 256, 0, stream>>>(h, W2, dis, xw2, n);
    k_agg64<<<(n + 7) / 8, 256, 0, stream>>>(xw2, dis, rowptr, csr, b2, out, n);
}

// Round 6
// 215.939 us; speedup vs baseline: 2.1687x; 1.0804x over previous
//
#include <hip/hip_runtime.h>
#include <hip/hip_fp16.h>

// GCN 2-layer. degree histogram (+edge rank) -> multi-block scan (fused
// rsqrt) -> atomic-free CSR fill -> [MFMA fp16 GEMM (scaled fp16 out) ->
// multi-node-per-wave aggregate] x2.
// out[i] = dis[i]*(scaled[i] + sum_{j in N(i)} scaled[j]) + b, with
// scaled[j] = dis[j]*(x[j]@W) written fp16 by the GEMM epilogue.
// Aggregation packs 4 (F=128) / 8 (F=64) nodes per wave so ONE gather
// instruction fetches 4/8 rows (16B/lane) — attacks memory-instruction
// issue count, which round-5 neutrality of ILP tweaks implicated.

typedef _Float16 half8 __attribute__((ext_vector_type(8)));
typedef float floatx4 __attribute__((ext_vector_type(4)));

__global__ void k_count(const int* __restrict__ col, int* __restrict__ deg,
                        int* __restrict__ rank, int E) {
    int e = blockIdx.x * blockDim.x + threadIdx.x;
    if (e < E) rank[e] = atomicAdd(&deg[col[e]], 1);
}

// Per-chunk inclusive scan + dis = rsqrt(deg+1) fused (reads deg anyway).
__global__ __launch_bounds__(1024) void k_scan_local(const int* __restrict__ deg,
                                                     int* __restrict__ rowptr,
                                                     int* __restrict__ bsum,
                                                     float* __restrict__ dis, int n) {
    __shared__ int s[1024];
    int b = blockIdx.x, tid = threadIdx.x;
    int i = b * 1024 + tid;
    int v = (i < n) ? deg[i] : 0;
    if (i < n) dis[i] = rsqrtf((float)v + 1.0f);  // +1 = self-loop
    s[tid] = v;
    __syncthreads();
    for (int off = 1; off < 1024; off <<= 1) {
        int t = (tid >= off) ? s[tid - off] : 0;
        __syncthreads();
        s[tid] += t;
        __syncthreads();
    }
    if (i < n) rowptr[i + 1] = s[tid];
    if (tid == 1023) bsum[b] = s[1023];
    if (b == 0 && tid == 0) rowptr[0] = 0;
}

__global__ __launch_bounds__(256) void k_scan_fix(int* __restrict__ rowptr,
                                                  const int* __restrict__ bsum, int n) {
    __shared__ int red[256];
    int b = blockIdx.x, tid = threadIdx.x;
    int partial = 0;
    for (int j = tid; j < b; j += 256) partial += bsum[j];
    red[tid] = partial;
    __syncthreads();
    for (int off = 128; off > 0; off >>= 1) {
        if (tid < off) red[tid] += red[tid + off];
        __syncthreads();
    }
    int offv = red[0];
    if (offv == 0) return;
#pragma unroll
    for (int r = 0; r < 4; ++r) {
        int i = b * 1024 + r * 256 + tid;
        if (i < n) rowptr[i + 1] += offv;
    }
}

// Atomic-free: position = rowptr[target] + precomputed rank.
__global__ void k_fill(const int* __restrict__ row, const int* __restrict__ col,
                       const int* __restrict__ rowptr, const int* __restrict__ rank,
                       int* __restrict__ csr, int E) {
    int e = blockIdx.x * blockDim.x + threadIdx.x;
    if (e < E) csr[rowptr[col[e]] + rank[e]] = row[e];
}

// Y[M,N](fp16) = (X[M,128] @ W[128,N]) * scale[m].
// Block: 64 rows (4 waves x 16), all N cols. K=128 in 4 MFMA steps of 32.
// LDS: Wt[n][k] fp16 as half2 dwords; 16B block (n,kblk) at dword
// n*64 + (kblk ^ (n&15))*4. XOR swizzle -> <=2-way banks (free) for both
// staging writes and ds_read_b128 B-frag reads.
// Frags (m89/m118/m120): A[m=lane&15][k=quad*8+j], B[k=quad*8+j][n=lane&15],
// D row=quad*4+reg, col=lane&15.
template <int N, typename AT>
__global__ __launch_bounds__(256) void k_gemm_mfma(const AT* __restrict__ X,
                                                   const float* __restrict__ W,
                                                   const float* __restrict__ scale,
                                                   __half* __restrict__ Y, int M) {
    __shared__ __align__(16) __half2 wt[N * 64];
    int tid = threadIdx.x;
    for (int i = tid; i < N * 64; i += 256) {
        int n = i & (N - 1);
        int k2 = i / N;  // k = 2*k2
        float w0 = W[(size_t)(2 * k2) * N + n];
        float w1 = W[(size_t)(2 * k2 + 1) * N + n];
        wt[n * 64 + ((k2 >> 2) ^ (n & 15)) * 4 + (k2 & 3)] = __floats2half2_rn(w0, w1);
    }
    __syncthreads();

    int wid = tid >> 6, lane = tid & 63;
    int col = lane & 15, quad = lane >> 4;
    int m_a = blockIdx.x * 64 + wid * 16 + col;
    bool a_ok = m_a < M;
    constexpr int NT = N / 16;
    floatx4 acc[NT] = {};
#pragma unroll
    for (int ks = 0; ks < 4; ++ks) {
        int k = ks * 32 + quad * 8;
        half8 af;
        if constexpr (sizeof(AT) == 4) {
            floatx4 a0 = {0.f, 0.f, 0.f, 0.f}, a1 = {0.f, 0.f, 0.f, 0.f};
            if (a_ok) {
                a0 = *(const floatx4*)&X[(size_t)m_a * 128 + k];
                a1 = *(const floatx4*)&X[(size_t)m_a * 128 + k + 4];
            }
            af = half8{(_Float16)a0[0], (_Float16)a0[1], (_Float16)a0[2], (_Float16)a0[3],
                       (_Float16)a1[0], (_Float16)a1[1], (_Float16)a1[2], (_Float16)a1[3]};
        } else {
            half8 t = {};
            if (a_ok) t = *(const half8*)(const void*)&X[(size_t)m_a * 128 + k];
            af = t;
        }
        int kblk = ks * 4 + quad;
#pragma unroll
        for (int nt = 0; nt < NT; ++nt) {
            int n = nt * 16 + col;
            half8 bf = *(const half8*)(const void*)&wt[n * 64 + (kblk ^ (n & 15)) * 4];
            acc[nt] = __builtin_amdgcn_mfma_f32_16x16x32_f16(af, bf, acc[nt], 0, 0, 0);
        }
    }
    int mbase = blockIdx.x * 64 + wid * 16 + quad * 4;
    float s[4];
#pragma unroll
    for (int r = 0; r < 4; ++r) s[r] = (mbase + r < M) ? scale[mbase + r] : 0.f;
#pragma unroll
    for (int nt = 0; nt < NT; ++nt) {
#pragma unroll
        for (int r = 0; r < 4; ++r) {
            if (mbase + r < M)
                Y[(size_t)(mbase + r) * N + nt * 16 + col] = __float2half(acc[nt][r] * s[r]);
        }
    }
}

// F=128: FOUR nodes per wave. Quarter-wave (16 lanes) x half8 (16B) = one
// 256B row -> each gather instruction fetches 4 rows (1KiB). Loop bound =
// max degree in the quad (butterfly shfl); OOB lanes gather row 0 (cached).
__global__ __launch_bounds__(256) void k_agg128(const __half* __restrict__ xw,
                                                const float* __restrict__ dis,
                                                const int* __restrict__ rowptr,
                                                const int* __restrict__ csr,
                                                const float* __restrict__ bias,
                                                __half* __restrict__ out, int n) {
    int tid = threadIdx.x;
    int lane = tid & 63;
    int q = lane >> 4, li = lane & 15;
    int node = blockIdx.x * 16 + ((tid >> 6) << 2) + q;
    bool ok = node < n;
    float di = 0.f;
    int beg = 0, end = 0;
    if (ok) {
        di = dis[node];
        beg = rowptr[node];
        end = rowptr[node + 1];
    }
    int deg = end - beg;
    int m1 = max(deg, __shfl(deg, lane ^ 16));
    int mx = max(m1, __shfl(m1, lane ^ 32));
    const half8* rows = (const half8*)xw;  // 16 half8 per row
    float acc[8] = {};
    if (ok) {
        half8 sf = rows[(size_t)node * 16 + li];
#pragma unroll
        for (int f = 0; f < 8; ++f) acc[f] = (float)sf[f];
    }
    int i = 0;
    for (; i + 8 <= mx; i += 8) {
        int s[8];
        half8 v[8];
#pragma unroll
        for (int j = 0; j < 8; ++j) {
            int e = beg + i + j;
            s[j] = (e < end) ? csr[e] : 0;
        }
#pragma unroll
        for (int j = 0; j < 8; ++j) v[j] = rows[(size_t)s[j] * 16 + li];
#pragma unroll
        for (int j = 0; j < 8; ++j) {
            if (beg + i + j < end) {
#pragma unroll
                for (int f = 0; f < 8; ++f) acc[f] += (float)v[j][f];
            }
        }
    }
    for (; i < mx; ++i) {
        int e = beg + i;
        int s = (e < end) ? csr[e] : 0;
        half8 v = rows[(size_t)s * 16 + li];
        if (e < end) {
#pragma unroll
            for (int f = 0; f < 8; ++f) acc[f] += (float)v[f];
        }
    }
    if (ok) {
        floatx4 b0 = *(const floatx4*)&bias[li * 8];
        floatx4 b1 = *(const floatx4*)&bias[li * 8 + 4];
        half8 o;
#pragma unroll
        for (int f = 0; f < 4; ++f) o[f] = (_Float16)fmaxf(acc[f] * di + b0[f], 0.f);
#pragma unroll
        for (int f = 0; f < 4; ++f) o[4 + f] = (_Float16)fmaxf(acc[4 + f] * di + b1[f], 0.f);
        ((half8*)out)[(size_t)node * 16 + li] = o;
    }
}

// F=64: EIGHT nodes per wave. Octet (8 lanes) x half8 (16B) = one 128B row
// -> each gather instruction fetches 8 rows (1KiB).
__global__ __launch_bounds__(256) void k_agg64(const __half* __restrict__ xw,
                                               const float* __restrict__ dis,
                                               const int* __restrict__ rowptr,
                                               const int* __restrict__ csr,
                                               const float* __restrict__ bias,
                                               float* __restrict__ out, int n) {
    int tid = threadIdx.x;
    int lane = tid & 63;
    int o8 = lane >> 3, li = lane & 7;
    int node = blockIdx.x * 32 + ((tid >> 6) << 3) + o8;
    bool ok = node < n;
    float di = 0.f;
    int beg = 0, end = 0;
    if (ok) {
        di = dis[node];
        beg = rowptr[node];
        end = rowptr[node + 1];
    }
    int deg = end - beg;
    int m1 = max(deg, __shfl(deg, lane ^ 8));
    int m2 = max(m1, __shfl(m1, lane ^ 16));
    int mx = max(m2, __shfl(m2, lane ^ 32));
    const half8* rows = (const half8*)xw;  // 8 half8 per row
    float acc[8] = {};
    if (ok) {
        half8 sf = rows[(size_t)node * 8 + li];
#pragma unroll
        for (int f = 0; f < 8; ++f) acc[f] = (float)sf[f];
    }
    int i = 0;
    for (; i + 8 <= mx; i += 8) {
        int s[8];
        half8 v[8];
#pragma unroll
        for (int j = 0; j < 8; ++j) {
            int e = beg + i + j;
            s[j] = (e < end) ? csr[e] : 0;
        }
#pragma unroll
        for (int j = 0; j < 8; ++j) v[j] = rows[(size_t)s[j] * 8 + li];
#pragma unroll
        for (int j = 0; j < 8; ++j) {
            if (beg + i + j < end) {
#pragma unroll
                for (int f = 0; f < 8; ++f) acc[f] += (float)v[j][f];
            }
        }
    }
    for (; i < mx; ++i) {
        int e = beg + i;
        int s = (e < end) ? csr[e] : 0;
        half8 v = rows[(size_t)s * 8 + li];
        if (e < end) {
#pragma unroll
            for (int f = 0; f < 8; ++f) acc[f] += (float)v[f];
        }
    }
    if (ok) {
        floatx4 b0 = *(const floatx4*)&bias[li * 8];
        floatx4 b1 = *(const floatx4*)&bias[li * 8 + 4];
        floatx4 o0, o1;
#pragma unroll
        for (int f = 0; f < 4; ++f) o0[f] = acc[f] * di + b0[f];
#pragma unroll
        for (int f = 0; f < 4; ++f) o1[f] = acc[4 + f] * di + b1[f];
        *(floatx4*)&out[(size_t)node * 64 + li * 8] = o0;
        *(floatx4*)&out[(size_t)node * 64 + li * 8 + 4] = o1;
    }
}

extern "C" void kernel_launch(void* const* d_in, const int* in_sizes, int n_in,
                              void* d_out, int out_size, void* d_ws, size_t ws_size,
                              hipStream_t stream) {
    const float* x  = (const float*)d_in[0];
    const int*   ei = (const int*)d_in[1];
    const float* W1 = (const float*)d_in[2];
    const float* b1 = (const float*)d_in[3];
    const float* W2 = (const float*)d_in[4];
    const float* b2 = (const float*)d_in[5];
    float* out = (float*)d_out;

    const int n = in_sizes[0] / 128;   // 50000
    const int E = in_sizes[1] / 2;     // 800000
    const int* row = ei;
    const int* col = ei + E;
    const int NB = (n + 1023) / 1024;

    char* ws = (char*)d_ws;
    size_t off = 0;
    auto alloc = [&](size_t bytes) -> void* {
        void* p = ws + off;
        off += (bytes + 255) & ~(size_t)255;
        return p;
    };
    int*    deg    = (int*)alloc((size_t)n * 4);
    int*    rowptr = (int*)alloc((size_t)(n + 1) * 4);
    int*    bsum   = (int*)alloc((size_t)NB * 4);
    int*    rank   = (int*)alloc((size_t)E * 4);
    int*    csr    = (int*)alloc((size_t)E * 4);
    float*  dis    = (float*)alloc((size_t)n * 4);
    __half* xw1    = (__half*)alloc((size_t)n * 128 * 2);
    __half* h      = (__half*)alloc((size_t)n * 128 * 2);
    __half* xw2    = (__half*)alloc((size_t)n * 64 * 2);
    (void)ws_size;

    hipMemsetAsync(deg, 0, (size_t)n * 4, stream);
    k_count<<<(E + 255) / 256, 256, 0, stream>>>(col, deg, rank, E);
    k_scan_local<<<NB, 1024, 0, stream>>>(deg, rowptr, bsum, dis, n);
    k_scan_fix<<<NB, 256, 0, stream>>>(rowptr, bsum, n);
    k_fill<<<(E + 255) / 256, 256, 0, stream>>>(row, col, rowptr, rank, csr, E);

    int gb = (n + 63) / 64;
    k_gemm_mfma<128, float><<<gb, 256, 0, stream>>>(x, W1, dis, xw1, n);
    k_agg128<<<(n + 15) / 16, 256, 0, stream>>>(xw1, dis, rowptr, csr, b1, h, n);

    k_gemm_mfma<64, __half><<<gb, 256, 0, stream>>>(h, W2, dis, xw2, n);
    k_agg64<<<(n + 31) / 32, 256, 0, stream>>>(xw2, dis, rowptr, csr, b2, out, n);
}